// Round 2
// baseline (711.777 us; speedup 1.0000x reference)
//
#include <hip/hip_runtime.h>
#include <hip/hip_fp16.h>

// GNN: 3x GCNConv (25->64->64->32) + global mean pool (256 graphs) + MLP head.
// Round 8: src-range-phased gather. R7 profile: F=64 gather FETCH_SIZE=315MB
// (77% L2 miss on the 12.8MB hp table -> L3 fetch path at 3.4TB/s = 92us of
// the 102us dispatch). Fix: CSR cols sorted by (dst, src-range) with 8 ranges
// of 16K nodes; gather runs as a fully-resident grid (<=2048 blocks, 64 VGPR
// cap, no LDS) holding per-node fp32 accumulators in registers and sweeping
// ranges in a phased outer loop. Instantaneous hp working set = 2MB per range
// -> fits 4MB per-XCD L2 -> fetch drops toward compulsory. fp16 payload kept.
// Assumes N < 2^17 (N=100000) for the 17-bit src packing.

#define IN_DIM 25
#define HID 64
#define OUT3 32
#define BK_LOG 7
#define BK_NODES 128
#define MAXB 1024
#define EPB1 16384
#define BCAP 8192
#define RNG_LOG 14      // src-range = src >> 14  (8 ranges cover N < 131072)
#define NR 8
#define NKEY (BK_NODES * NR)

__device__ inline int ld_nt_i32(const int* p) {
    return __builtin_nontemporal_load(p);
}

// ---------------- stage 1: bucket histogram (LDS-privatized) ----------------
__global__ __launch_bounds__(256) void bucket_hist(const int* __restrict__ dst,
                                                   int* __restrict__ bhist, int nE) {
    __shared__ int h[MAXB];
    for (int i = threadIdx.x; i < MAXB; i += 256) h[i] = 0;
    __syncthreads();
    int e0 = blockIdx.x * 8192;
    int cnt = min(8192, nE - e0);
    for (int i = threadIdx.x; i < cnt; i += 256)
        atomicAdd(&h[(unsigned)dst[e0 + i] >> BK_LOG], 1);
    __syncthreads();
    for (int i = threadIdx.x; i < MAXB; i += 256)
        if (h[i]) atomicAdd(&bhist[i], h[i]);
}

// ---------------- stage 2: scan bucket counts (1 block) ----------------
__global__ __launch_bounds__(256) void bucket_scan(const int* __restrict__ bhist,
                                                   int* __restrict__ bbase,
                                                   int* __restrict__ cursor,
                                                   int nb, int nE) {
    __shared__ int s4[256];
    int t = threadIdx.x;
    int v[4]; int sum = 0;
#pragma unroll
    for (int j = 0; j < 4; ++j) {
        int b = 4 * t + j;
        v[j] = (b < nb) ? bhist[b] : 0;
        sum += v[j];
    }
    s4[t] = sum;
    __syncthreads();
    for (int off = 1; off < 256; off <<= 1) {
        int mine = s4[t];
        int add = (t >= off) ? s4[t - off] : 0;
        __syncthreads();
        s4[t] = mine + add;
        __syncthreads();
    }
    int run = s4[t] - sum;
#pragma unroll
    for (int j = 0; j < 4; ++j) {
        int b = 4 * t + j;
        if (b < nb) { bbase[b] = run; cursor[b] = run; }
        run += v[j];
    }
    if (t == 0) bbase[nb] = nE;
}

// ---------------- stage 3: partition edges into buckets (coalesced) --------
__global__ __launch_bounds__(256) void partition_kernel(
        const int* __restrict__ src, const int* __restrict__ dst,
        int* __restrict__ cursor, unsigned int* __restrict__ ebuf, int nE) {
    __shared__ int lh[MAXB];
    __shared__ int lrun[MAXB];
    __shared__ int lcur[MAXB];
    __shared__ int swp[256];
    __shared__ unsigned int stg[EPB1];
    __shared__ unsigned short sbk[EPB1];
    int t = threadIdx.x;
    int e0 = blockIdx.x * EPB1;
    int cnt = min(EPB1, nE - e0);
    for (int i = t; i < MAXB; i += 256) lh[i] = 0;
    __syncthreads();
    for (int i = t; i < cnt; i += 256)
        atomicAdd(&lh[(unsigned)dst[e0 + i] >> BK_LOG], 1);
    __syncthreads();
    int v[4]; int sum = 0;
#pragma unroll
    for (int j = 0; j < 4; ++j) { v[j] = lh[4 * t + j]; sum += v[j]; }
    swp[t] = sum;
    __syncthreads();
    for (int off = 1; off < 256; off <<= 1) {
        int mine = swp[t];
        int add = (t >= off) ? swp[t - off] : 0;
        __syncthreads();
        swp[t] = mine + add;
        __syncthreads();
    }
    int run = swp[t] - sum;
#pragma unroll
    for (int j = 0; j < 4; ++j) {
        int b = 4 * t + j;
        lh[b] = run;
        lcur[b] = 0;
        if (v[j] > 0) lrun[b] = atomicAdd(&cursor[b], v[j]);
        run += v[j];
    }
    __syncthreads();
    for (int i = t; i < cnt; i += 256) {
        int d = dst[e0 + i];
        int s = src[e0 + i];
        int b = (unsigned)d >> BK_LOG;
        int lp = atomicAdd(&lcur[b], 1);
        int slot = lh[b] + lp;
        stg[slot] = ((unsigned)(d & (BK_NODES - 1)) << 17) | (unsigned)s;
        sbk[slot] = (unsigned short)b;
    }
    __syncthreads();
    for (int i = t; i < cnt; i += 256) {
        int b = sbk[i];
        int g = lrun[b] + (i - lh[b]);
        ebuf[g] = stg[i];
    }
}

// ------- stage 4: per-bucket CSR sort by (dst-local, src-range) + rps ------
// rps[r*nN + node] = start of range r within node's row (r = 0..7);
// rps[8*nN + node] = row end. dinv from row degree.
__global__ __launch_bounds__(256) void bucket_csr_kernel(
        unsigned int* __restrict__ ebuf, const int* __restrict__ bbase,
        float* __restrict__ dinv, int* __restrict__ rps, int nN) {
    int b = blockIdx.x;
    int node_lo = b << BK_LOG;
    int nn = min(BK_NODES, nN - node_lo);
    int base = bbase[b];
    int cnt = bbase[b + 1] - base;
    if (cnt > BCAP) cnt = BCAP;
    __shared__ unsigned int in[BCAP];
    __shared__ unsigned int outb[BCAP];
    __shared__ int h[NKEY], sc[NKEY], lc[NKEY];
    __shared__ int swp[256];
    int t = threadIdx.x;
    for (int i = t; i < cnt; i += 256) in[i] = ebuf[base + i];
    for (int i = t; i < NKEY; i += 256) { h[i] = 0; lc[i] = 0; }
    __syncthreads();
    for (int i = t; i < cnt; i += 256) {
        unsigned int w = in[i];
        int kk = (int)((w >> 17) << 3) | (int)((w & 0x1FFFFu) >> RNG_LOG);
        atomicAdd(&h[kk], 1);
    }
    __syncthreads();
    int v[4]; int sum = 0;
#pragma unroll
    for (int j = 0; j < 4; ++j) { v[j] = h[4 * t + j]; sum += v[j]; }
    swp[t] = sum;
    __syncthreads();
    for (int off = 1; off < 256; off <<= 1) {
        int mine = swp[t];
        int add = (t >= off) ? swp[t - off] : 0;
        __syncthreads();
        swp[t] = mine + add;
        __syncthreads();
    }
    int run = swp[t] - sum;
#pragma unroll
    for (int j = 0; j < 4; ++j) { sc[4 * t + j] = run; run += v[j]; }
    __syncthreads();
    // per-(node,range) start pointers
    for (int kk = t; kk < NKEY; kk += 256) {
        int dl = kk >> 3;
        if (dl < nn) rps[(size_t)(kk & 7) * nN + node_lo + dl] = base + sc[kk];
    }
    // per-node: row end + dinv
    if (t < BK_NODES && t < nn) {
        int s0 = sc[t << 3];
        int e7 = sc[(t << 3) + 7] + h[(t << 3) + 7];
        rps[(size_t)8 * nN + node_lo + t] = base + e7;
        dinv[node_lo + t] = rsqrtf((float)(e7 - s0) + 1.0f);
    }
    __syncthreads();
    for (int i = t; i < cnt; i += 256) {
        unsigned int w = in[i];
        int kk = (int)((w >> 17) << 3) | (int)((w & 0x1FFFFu) >> RNG_LOG);
        int lp = atomicAdd(&lc[kk], 1);
        outb[sc[kk] + lp] = w & 0x1FFFFu;
    }
    __syncthreads();
    for (int i = t; i < cnt; i += 256) ebuf[base + i] = outb[i];
}

// ---------------- pad + pre-scale helpers ----------------
// xp[node][c] = half( x[node][c] * dinv[node] )  (pre-scaled gather operand)
__global__ void padx_kernel(const float* __restrict__ x, const float* __restrict__ dinv,
                            __half* __restrict__ xp, int n) {
    int i = blockIdx.x * 256 + threadIdx.x;   // one thread per 2 cols
    if (i < n * 16) {
        int node = i >> 4, c2 = (i & 15) * 2;
        float s = dinv[node];
        float v0 = (c2     < IN_DIM) ? x[(size_t)node * IN_DIM + c2    ] * s : 0.f;
        float v1 = (c2 + 1 < IN_DIM) ? x[(size_t)node * IN_DIM + c2 + 1] * s : 0.f;
        *(__half2*)&xp[(size_t)node * 32 + c2] = __floats2half2_rn(v0, v1);
    }
}

__global__ void padw_kernel(const float* __restrict__ W1, float* __restrict__ W1p) {
    int i = blockIdx.x * 256 + threadIdx.x;
    if (i < 32 * HID) {
        int r = i >> 6, c = i & 63;
        W1p[i] = (r < IN_DIM) ? W1[r * HID + c] : 0.f;
    }
}

// ---------------- dense layer: out = in @ W [*dinv->half] [+bias,relu] -----
// SCALE=true writes __half (gather operand); SCALE=false writes float.
template<int INF, int OUTF, bool ACT, bool SCALE>
__global__ __launch_bounds__(256) void gemm_kernel(
        const float* __restrict__ in, const float* __restrict__ W,
        const float* __restrict__ bias, const float* __restrict__ dinv,
        void* __restrict__ out, int n) {
    constexpr int TPN = OUTF / 4;
    constexpr int NPB = 256 / TPN;
    constexpr int LDK = INF + 4;
    __shared__ float sW[INF * OUTF];
    __shared__ float sIn[NPB][LDK];
    for (int i = threadIdx.x; i < INF * OUTF; i += 256) sW[i] = W[i];
    int node0 = blockIdx.x * NPB;
    for (int i = threadIdx.x; i < NPB * INF; i += 256) {
        int ln = i / INF, k = i % INF;
        int node = node0 + ln;
        sIn[ln][k] = (node < n) ? in[(size_t)node * INF + k] : 0.f;
    }
    __syncthreads();
    int g   = threadIdx.x / TPN;
    int of0 = (threadIdx.x % TPN) * 4;
    int node = node0 + g;
    float4 acc = make_float4(0.f, 0.f, 0.f, 0.f);
#pragma unroll
    for (int k = 0; k < INF; ++k) {
        float aj = sIn[g][k];
        const float4 wv = *(const float4*)&sW[k * OUTF + of0];
        acc.x += aj * wv.x; acc.y += aj * wv.y;
        acc.z += aj * wv.z; acc.w += aj * wv.w;
    }
    if (ACT) {
        const float4 bv = *(const float4*)&bias[of0];
        acc.x = fmaxf(acc.x + bv.x, 0.f);
        acc.y = fmaxf(acc.y + bv.y, 0.f);
        acc.z = fmaxf(acc.z + bv.z, 0.f);
        acc.w = fmaxf(acc.w + bv.w, 0.f);
    }
    if (node < n) {
        if (SCALE) {
            float s = dinv[node];
            union { __half2 h[2]; uint2 u; } pk;
            pk.h[0] = __floats2half2_rn(acc.x * s, acc.y * s);
            pk.h[1] = __floats2half2_rn(acc.z * s, acc.w * s);
            *(uint2*)((__half*)out + (size_t)node * OUTF + of0) = pk.u;
        } else {
            *(float4*)((float*)out + (size_t)node * OUTF + of0) = acc;
        }
    }
}

// ---------------- src-range-phased CSR gather on PRE-SCALED fp16 rows ------
// out[d] = act( dinv[d] * (hp[d] + sum_cols hp[c]) + bias )
// Grid is fully resident; each lane holds float2 accumulators for K nodes in
// registers; outer loop sweeps the 8 src-ranges so the instantaneous hp
// working set (2MB at F=64) fits per-XCD L2.
template<int F, bool ACT, int K>
__global__ __launch_bounds__(256, 8) void gather_kernel(
        const __half* __restrict__ hp, const float* __restrict__ dinv,
        const int* __restrict__ rps, const int* __restrict__ col,
        const float* __restrict__ bias, float* __restrict__ agg, int n) {
    constexpr int LPN = F / 2;          // lanes per node (half2 per lane)
    constexpr int SPW = 64 / LPN;       // node slots per wave
    int wid  = (blockIdx.x * 256 + threadIdx.x) >> 6;
    int lane = threadIdx.x & 63;
    int sub  = lane / LPN;
    int f2   = lane % LPN;
    int n0   = (wid * SPW + sub) * K;   // first node of this slot (contiguous K)
    float ax[K], ay[K];
    // self-loop init (pre-scaled rows)
#pragma unroll
    for (int k = 0; k < K; ++k) {
        ax[k] = 0.f; ay[k] = 0.f;
        int nk = n0 + k;
        if (nk < n) {
            float2 v = __half22float2(*(const __half2*)&hp[(size_t)nk * F + 2 * f2]);
            ax[k] = v.x; ay[k] = v.y;
        }
    }
    for (int r = 0; r < NR; ++r) {
        const int* rs = rps + (size_t)r * n;
        const int* re = rps + (size_t)(r + 1) * n;
#pragma unroll
        for (int k = 0; k < K; ++k) {
            int nk = n0 + k;
            if (nk < n) {
                int e = rs[nk], e1 = re[nk];
                for (; e + 4 <= e1; e += 4) {
                    int c0 = ld_nt_i32(&col[e]);
                    int c1 = ld_nt_i32(&col[e + 1]);
                    int c2 = ld_nt_i32(&col[e + 2]);
                    int c3 = ld_nt_i32(&col[e + 3]);
                    float2 v0 = __half22float2(*(const __half2*)&hp[(size_t)c0 * F + 2 * f2]);
                    float2 v1 = __half22float2(*(const __half2*)&hp[(size_t)c1 * F + 2 * f2]);
                    float2 v2 = __half22float2(*(const __half2*)&hp[(size_t)c2 * F + 2 * f2]);
                    float2 v3 = __half22float2(*(const __half2*)&hp[(size_t)c3 * F + 2 * f2]);
                    ax[k] += (v0.x + v1.x) + (v2.x + v3.x);
                    ay[k] += (v0.y + v1.y) + (v2.y + v3.y);
                }
                for (; e < e1; ++e) {
                    int c = ld_nt_i32(&col[e]);
                    float2 v = __half22float2(*(const __half2*)&hp[(size_t)c * F + 2 * f2]);
                    ax[k] += v.x; ay[k] += v.y;
                }
            }
        }
        __syncthreads();   // keep the block's waves range-phased
    }
#pragma unroll
    for (int k = 0; k < K; ++k) {
        int nk = n0 + k;
        if (nk < n) {
            float s = dinv[nk];
            float rx = ax[k] * s, ry = ay[k] * s;
            if (ACT) {
                rx = fmaxf(rx + bias[2 * f2], 0.f);
                ry = fmaxf(ry + bias[2 * f2 + 1], 0.f);
            }
            *(float2*)&agg[(size_t)nk * F + 2 * f2] = make_float2(rx, ry);
        }
    }
}

// ---------------- mean pool ----------------
__global__ __launch_bounds__(256) void pool_kernel(
        const float* __restrict__ h3, const int* __restrict__ batch,
        int n, float* __restrict__ pool) {
    int g = blockIdx.x;
    int lo = 0, hi = n;
    while (lo < hi) { int m = (lo + hi) >> 1; if (batch[m] < g) lo = m + 1; else hi = m; }
    int s = lo;
    hi = n;
    while (lo < hi) { int m = (lo + hi) >> 1; if (batch[m] < g + 1) lo = m + 1; else hi = m; }
    int e = lo;
    constexpr int F = OUT3;
    int ln = threadIdx.x / F;
    int f  = threadIdx.x % F;
    float acc = 0.f;
    for (int i = s + ln; i < e; i += 8)
        acc += h3[(size_t)i * F + f];
    __shared__ float red[8][F];
    red[ln][f] = acc;
    __syncthreads();
    if (ln == 0) {
        float t = 0.f;
#pragma unroll
        for (int j = 0; j < 8; ++j) t += red[j][f];
        float cnt = (float)((e - s) > 0 ? (e - s) : 1);
        pool[g * F + f] = t / cnt;
    }
}

// ---------------- head ----------------
__global__ __launch_bounds__(256) void head_kernel(
        const float* __restrict__ pool, const float* __restrict__ Wh1,
        const float* __restrict__ bh1, const float* __restrict__ Wh2,
        const float* __restrict__ bh2, float* __restrict__ out) {
    __shared__ float sW1[32 * 32];
    __shared__ float sb1[32];
    __shared__ float sW2[32];
    int t = threadIdx.x;
    for (int i = t; i < 1024; i += 256) sW1[i] = Wh1[i];
    if (t < 32) { sb1[t] = bh1[t]; sW2[t] = Wh2[t]; }
    __syncthreads();
    int g = t;
    float y = bh2[0];
    const float* p = &pool[g * 32];
#pragma unroll 4
    for (int j = 0; j < 32; ++j) {
        float a = sb1[j];
#pragma unroll
        for (int k = 0; k < 32; ++k) a += p[k] * sW1[k * 32 + j];
        y += fmaxf(a, 0.f) * sW2[j];
    }
    out[g] = y;
}

extern "C" void kernel_launch(void* const* d_in, const int* in_sizes, int n_in,
                              void* d_out, int out_size, void* d_ws, size_t ws_size,
                              hipStream_t stream) {
    const float* x    = (const float*)d_in[0];
    const int*   ei   = (const int*)  d_in[1];
    const int*   batch= (const int*)  d_in[2];
    const float* W1   = (const float*)d_in[3];
    const float* b1   = (const float*)d_in[4];
    const float* W2   = (const float*)d_in[5];
    const float* b2   = (const float*)d_in[6];
    const float* W3   = (const float*)d_in[7];
    const float* b3   = (const float*)d_in[8];
    const float* Wh1  = (const float*)d_in[9];
    const float* bh1  = (const float*)d_in[10];
    const float* Wh2  = (const float*)d_in[11];
    const float* bh2  = (const float*)d_in[12];
    float* out = (float*)d_out;

    const int N = in_sizes[0] / IN_DIM;
    const int E = in_sizes[1] / 2;
    const int* src = ei;
    const int* dst = ei + E;
    const int NB = (N + BK_NODES - 1) >> BK_LOG;

    // workspace layout (all 4B elements; half buffers alias the fp32 ones)
    char* base = (char*)d_ws;
    unsigned int* ebuf = (unsigned int*)base;       base += (size_t)E * 4;
    int*   bhist   = (int*)base;                    base += (size_t)MAXB * 4;
    int*   bbase   = (int*)base;                    base += (size_t)(MAXB + 1) * 4;
    int*   cursor  = (int*)base;                    base += (size_t)MAXB * 4;
    int*   rps     = (int*)base;                    base += (size_t)(NR + 1) * N * 4;
    float* dinv    = (float*)base;                  base += (size_t)N * 4;
    float* W1p     = (float*)base;                  base += (size_t)32 * HID * 4;
    float* bufA    = (float*)base;                  base += (size_t)N * HID * 4;
    float* bufB    = (float*)base;                  base += (size_t)N * HID * 4;
    float* pool    = (float*)base;

    // ---- CSR build (coalesced counting sort, cols grouped by src-range) ----
    hipMemsetAsync(bhist, 0, (size_t)MAXB * sizeof(int), stream);
    bucket_hist<<<(E + 8191) / 8192, 256, 0, stream>>>(dst, bhist, E);
    bucket_scan<<<1, 256, 0, stream>>>(bhist, bbase, cursor, NB, E);
    partition_kernel<<<(E + EPB1 - 1) / EPB1, 256, 0, stream>>>(src, dst, cursor, ebuf, E);
    bucket_csr_kernel<<<NB, 256, 0, stream>>>(ebuf, bbase, dinv, rps, N);
    const int* col = (const int*)ebuf;

    // gather grid sizing: nodes per block = 4 waves * SPW * K
    constexpr int K64 = 7, K32 = 4;
    const int npb64 = 4 * 2 * K64;   // 56
    const int npb32 = 4 * 4 * K32;   // 64
    const int blocks64 = (N + npb64 - 1) / npb64;
    const int blocks32 = (N + npb32 - 1) / npb32;

    // ---- layer 1 (reordered): aggX = A_hat Xp' ; h1 = relu(aggX @ W1p + b1)
    // xp (half) in bufB; aggX (fp32) in bufA; h1 (fp32) back in bufB.
    padx_kernel<<<((size_t)N * 16 + 255) / 256, 256, 0, stream>>>(x, dinv, (__half*)bufB, N);
    padw_kernel<<<(32 * HID + 255) / 256, 256, 0, stream>>>(W1, W1p);
    gather_kernel<32, false, K32><<<blocks32, 256, 0, stream>>>((const __half*)bufB, dinv, rps, col, nullptr, bufA, N);
    gemm_kernel<32, HID, true, false><<<(N + 15) / 16, 256, 0, stream>>>(bufA, W1p, b1, nullptr, bufB, N);

    // ---- layer 2: t2' = half((h1 @ W2)*dinv) ; h2 = relu(dinv*(sum t2') + b2)
    gemm_kernel<HID, HID, false, true><<<(N + 15) / 16, 256, 0, stream>>>(bufB, W2, nullptr, dinv, bufA, N);
    gather_kernel<HID, true, K64><<<blocks64, 256, 0, stream>>>((const __half*)bufA, dinv, rps, col, b2, bufB, N);

    // ---- layer 3: t3' = half((h2 @ W3)*dinv) ; h3 = relu(dinv*(sum t3') + b3)
    gemm_kernel<HID, OUT3, false, true><<<(N + 31) / 32, 256, 0, stream>>>(bufB, W3, nullptr, dinv, bufA, N);
    gather_kernel<OUT3, true, K32><<<blocks32, 256, 0, stream>>>((const __half*)bufA, dinv, rps, col, b3, bufB, N);

    // ---- pool + head ----
    pool_kernel<<<256, 256, 0, stream>>>(bufB, batch, N, pool);
    head_kernel<<<1, 256, 0, stream>>>(pool, Wh1, bh1, Wh2, bh2, out);
}

// Round 4
// 705.566 us; speedup vs baseline: 1.0088x; 1.0088x over previous
//
#include <hip/hip_runtime.h>
#include <hip/hip_fp16.h>

// GNN: 3x GCNConv (25->64->64->32) + global mean pool (256 graphs) + MLP head.
// Round 9b: phased gather with cross-segment MLP (R9 resubmit; infra failed).
// R8 proved src-range phasing reaches compulsory fetch (130MB) but collapsed
// memory-level parallelism (4-edge segments behind dependent rps/col/data
// chains -> 195us latency-bound). R9 keeps the phasing and restores MLP:
// each thread owns K=6 nodes = 6 independent segments per range, processed
// in lockstep rounds of 2 clamped+predicated edges per segment (24
// independent loads in flight, compile-time indexed). Range bounds chain
// (end(r)=start(r+1)) with a 1-plane prefetch hides boundary latency.
// launch_bounds(256,4): K=6 state (~50 VGPR) would spill under the 64-VGPR
// budget of (256,8); 128 VGPR + 24-deep per-thread MLP >> occupancy.
// agg stores are nontemporal so the output stream doesn't evict the phased
// hp window from L2. Assumes N < 2^17 for the 17-bit src packing.

#define IN_DIM 25
#define HID 64
#define OUT3 32
#define BK_LOG 7
#define BK_NODES 128
#define MAXB 1024
#define EPB1 16384
#define BCAP 8192
#define RNG_LOG 14      // src-range = src >> 14  (8 ranges cover N < 131072)
#define NR 8
#define NKEY (BK_NODES * NR)

__device__ inline int ld_nt_i32(const int* p) {
    return __builtin_nontemporal_load(p);
}

// ---------------- stage 1: bucket histogram (LDS-privatized) ----------------
__global__ __launch_bounds__(256) void bucket_hist(const int* __restrict__ dst,
                                                   int* __restrict__ bhist, int nE) {
    __shared__ int h[MAXB];
    for (int i = threadIdx.x; i < MAXB; i += 256) h[i] = 0;
    __syncthreads();
    int e0 = blockIdx.x * 8192;
    int cnt = min(8192, nE - e0);
    for (int i = threadIdx.x; i < cnt; i += 256)
        atomicAdd(&h[(unsigned)dst[e0 + i] >> BK_LOG], 1);
    __syncthreads();
    for (int i = threadIdx.x; i < MAXB; i += 256)
        if (h[i]) atomicAdd(&bhist[i], h[i]);
}

// ---------------- stage 2: scan bucket counts (1 block) ----------------
__global__ __launch_bounds__(256) void bucket_scan(const int* __restrict__ bhist,
                                                   int* __restrict__ bbase,
                                                   int* __restrict__ cursor,
                                                   int nb, int nE) {
    __shared__ int s4[256];
    int t = threadIdx.x;
    int v[4]; int sum = 0;
#pragma unroll
    for (int j = 0; j < 4; ++j) {
        int b = 4 * t + j;
        v[j] = (b < nb) ? bhist[b] : 0;
        sum += v[j];
    }
    s4[t] = sum;
    __syncthreads();
    for (int off = 1; off < 256; off <<= 1) {
        int mine = s4[t];
        int add = (t >= off) ? s4[t - off] : 0;
        __syncthreads();
        s4[t] = mine + add;
        __syncthreads();
    }
    int run = s4[t] - sum;
#pragma unroll
    for (int j = 0; j < 4; ++j) {
        int b = 4 * t + j;
        if (b < nb) { bbase[b] = run; cursor[b] = run; }
        run += v[j];
    }
    if (t == 0) bbase[nb] = nE;
}

// ---------------- stage 3: partition edges into buckets (coalesced) --------
__global__ __launch_bounds__(256) void partition_kernel(
        const int* __restrict__ src, const int* __restrict__ dst,
        int* __restrict__ cursor, unsigned int* __restrict__ ebuf, int nE) {
    __shared__ int lh[MAXB];
    __shared__ int lrun[MAXB];
    __shared__ int lcur[MAXB];
    __shared__ int swp[256];
    __shared__ unsigned int stg[EPB1];
    __shared__ unsigned short sbk[EPB1];
    int t = threadIdx.x;
    int e0 = blockIdx.x * EPB1;
    int cnt = min(EPB1, nE - e0);
    for (int i = t; i < MAXB; i += 256) lh[i] = 0;
    __syncthreads();
    for (int i = t; i < cnt; i += 256)
        atomicAdd(&lh[(unsigned)dst[e0 + i] >> BK_LOG], 1);
    __syncthreads();
    int v[4]; int sum = 0;
#pragma unroll
    for (int j = 0; j < 4; ++j) { v[j] = lh[4 * t + j]; sum += v[j]; }
    swp[t] = sum;
    __syncthreads();
    for (int off = 1; off < 256; off <<= 1) {
        int mine = swp[t];
        int add = (t >= off) ? swp[t - off] : 0;
        __syncthreads();
        swp[t] = mine + add;
        __syncthreads();
    }
    int run = swp[t] - sum;
#pragma unroll
    for (int j = 0; j < 4; ++j) {
        int b = 4 * t + j;
        lh[b] = run;
        lcur[b] = 0;
        if (v[j] > 0) lrun[b] = atomicAdd(&cursor[b], v[j]);
        run += v[j];
    }
    __syncthreads();
    for (int i = t; i < cnt; i += 256) {
        int d = dst[e0 + i];
        int s = src[e0 + i];
        int b = (unsigned)d >> BK_LOG;
        int lp = atomicAdd(&lcur[b], 1);
        int slot = lh[b] + lp;
        stg[slot] = ((unsigned)(d & (BK_NODES - 1)) << 17) | (unsigned)s;
        sbk[slot] = (unsigned short)b;
    }
    __syncthreads();
    for (int i = t; i < cnt; i += 256) {
        int b = sbk[i];
        int g = lrun[b] + (i - lh[b]);
        ebuf[g] = stg[i];
    }
}

// ------- stage 4: per-bucket CSR sort by (dst-local, src-range) + rps ------
// rps[r*nN + node] = start of range r within node's row (r = 0..7);
// rps[8*nN + node] = row end. dinv from row degree.
__global__ __launch_bounds__(256) void bucket_csr_kernel(
        unsigned int* __restrict__ ebuf, const int* __restrict__ bbase,
        float* __restrict__ dinv, int* __restrict__ rps, int nN) {
    int b = blockIdx.x;
    int node_lo = b << BK_LOG;
    int nn = min(BK_NODES, nN - node_lo);
    int base = bbase[b];
    int cnt = bbase[b + 1] - base;
    if (cnt > BCAP) cnt = BCAP;
    __shared__ unsigned int in[BCAP];
    __shared__ unsigned int outb[BCAP];
    __shared__ int h[NKEY], sc[NKEY], lc[NKEY];
    __shared__ int swp[256];
    int t = threadIdx.x;
    for (int i = t; i < cnt; i += 256) in[i] = ebuf[base + i];
    for (int i = t; i < NKEY; i += 256) { h[i] = 0; lc[i] = 0; }
    __syncthreads();
    for (int i = t; i < cnt; i += 256) {
        unsigned int w = in[i];
        int kk = (int)((w >> 17) << 3) | (int)((w & 0x1FFFFu) >> RNG_LOG);
        atomicAdd(&h[kk], 1);
    }
    __syncthreads();
    int v[4]; int sum = 0;
#pragma unroll
    for (int j = 0; j < 4; ++j) { v[j] = h[4 * t + j]; sum += v[j]; }
    swp[t] = sum;
    __syncthreads();
    for (int off = 1; off < 256; off <<= 1) {
        int mine = swp[t];
        int add = (t >= off) ? swp[t - off] : 0;
        __syncthreads();
        swp[t] = mine + add;
        __syncthreads();
    }
    int run = swp[t] - sum;
#pragma unroll
    for (int j = 0; j < 4; ++j) { sc[4 * t + j] = run; run += v[j]; }
    __syncthreads();
    // per-(node,range) start pointers
    for (int kk = t; kk < NKEY; kk += 256) {
        int dl = kk >> 3;
        if (dl < nn) rps[(size_t)(kk & 7) * nN + node_lo + dl] = base + sc[kk];
    }
    // per-node: row end + dinv
    if (t < BK_NODES && t < nn) {
        int s0 = sc[t << 3];
        int e7 = sc[(t << 3) + 7] + h[(t << 3) + 7];
        rps[(size_t)8 * nN + node_lo + t] = base + e7;
        dinv[node_lo + t] = rsqrtf((float)(e7 - s0) + 1.0f);
    }
    __syncthreads();
    for (int i = t; i < cnt; i += 256) {
        unsigned int w = in[i];
        int kk = (int)((w >> 17) << 3) | (int)((w & 0x1FFFFu) >> RNG_LOG);
        int lp = atomicAdd(&lc[kk], 1);
        outb[sc[kk] + lp] = w & 0x1FFFFu;
    }
    __syncthreads();
    for (int i = t; i < cnt; i += 256) ebuf[base + i] = outb[i];
}

// ---------------- pad + pre-scale helpers ----------------
// xp[node][c] = half( x[node][c] * dinv[node] )  (pre-scaled gather operand)
__global__ void padx_kernel(const float* __restrict__ x, const float* __restrict__ dinv,
                            __half* __restrict__ xp, int n) {
    int i = blockIdx.x * 256 + threadIdx.x;   // one thread per 2 cols
    if (i < n * 16) {
        int node = i >> 4, c2 = (i & 15) * 2;
        float s = dinv[node];
        float v0 = (c2     < IN_DIM) ? x[(size_t)node * IN_DIM + c2    ] * s : 0.f;
        float v1 = (c2 + 1 < IN_DIM) ? x[(size_t)node * IN_DIM + c2 + 1] * s : 0.f;
        *(__half2*)&xp[(size_t)node * 32 + c2] = __floats2half2_rn(v0, v1);
    }
}

__global__ void padw_kernel(const float* __restrict__ W1, float* __restrict__ W1p) {
    int i = blockIdx.x * 256 + threadIdx.x;
    if (i < 32 * HID) {
        int r = i >> 6, c = i & 63;
        W1p[i] = (r < IN_DIM) ? W1[r * HID + c] : 0.f;
    }
}

// ---------------- dense layer: out = in @ W [*dinv->half] [+bias,relu] -----
// SCALE=true writes __half (gather operand); SCALE=false writes float.
template<int INF, int OUTF, bool ACT, bool SCALE>
__global__ __launch_bounds__(256) void gemm_kernel(
        const float* __restrict__ in, const float* __restrict__ W,
        const float* __restrict__ bias, const float* __restrict__ dinv,
        void* __restrict__ out, int n) {
    constexpr int TPN = OUTF / 4;
    constexpr int NPB = 256 / TPN;
    constexpr int LDK = INF + 4;
    __shared__ float sW[INF * OUTF];
    __shared__ float sIn[NPB][LDK];
    for (int i = threadIdx.x; i < INF * OUTF; i += 256) sW[i] = W[i];
    int node0 = blockIdx.x * NPB;
    for (int i = threadIdx.x; i < NPB * INF; i += 256) {
        int ln = i / INF, k = i % INF;
        int node = node0 + ln;
        sIn[ln][k] = (node < n) ? in[(size_t)node * INF + k] : 0.f;
    }
    __syncthreads();
    int g   = threadIdx.x / TPN;
    int of0 = (threadIdx.x % TPN) * 4;
    int node = node0 + g;
    float4 acc = make_float4(0.f, 0.f, 0.f, 0.f);
#pragma unroll
    for (int k = 0; k < INF; ++k) {
        float aj = sIn[g][k];
        const float4 wv = *(const float4*)&sW[k * OUTF + of0];
        acc.x += aj * wv.x; acc.y += aj * wv.y;
        acc.z += aj * wv.z; acc.w += aj * wv.w;
    }
    if (ACT) {
        const float4 bv = *(const float4*)&bias[of0];
        acc.x = fmaxf(acc.x + bv.x, 0.f);
        acc.y = fmaxf(acc.y + bv.y, 0.f);
        acc.z = fmaxf(acc.z + bv.z, 0.f);
        acc.w = fmaxf(acc.w + bv.w, 0.f);
    }
    if (node < n) {
        if (SCALE) {
            float s = dinv[node];
            union { __half2 h[2]; uint2 u; } pk;
            pk.h[0] = __floats2half2_rn(acc.x * s, acc.y * s);
            pk.h[1] = __floats2half2_rn(acc.z * s, acc.w * s);
            *(uint2*)((__half*)out + (size_t)node * OUTF + of0) = pk.u;
        } else {
            *(float4*)((float*)out + (size_t)node * OUTF + of0) = acc;
        }
    }
}

// ------- src-range-phased CSR gather, cross-segment MLP, fp16 rows ---------
// out[d] = act( dinv[d] * (hp[d] + sum_cols hp[c]) + bias )
// Per thread: K nodes = K independent segments per range, advanced in
// lockstep rounds of 2 clamped+predicated edges each (2K col + 2K data
// independent loads in flight). end(r) == start(r+1), so bounds chain with a
// single prefetched plane per range.
template<int F, bool ACT, int K>
__global__ __launch_bounds__(256, 4) void gather_kernel(
        const __half* __restrict__ hp, const float* __restrict__ dinv,
        const int* __restrict__ rps, const int* __restrict__ col,
        const float* __restrict__ bias, float* __restrict__ agg, int n) {
    constexpr int LPN = F / 2;          // lanes per node (half2 per lane)
    constexpr int SPW = 64 / LPN;       // node slots per wave
    int wid  = (blockIdx.x * 256 + threadIdx.x) >> 6;
    int lane = threadIdx.x & 63;
    int sub  = lane / LPN;
    int f2   = lane % LPN;
    int n0   = (wid * SPW + sub) * K;   // first node of this slot
    float ax[K], ay[K];
    int cur[K], end_[K], nxt[K];
#pragma unroll
    for (int k = 0; k < K; ++k) {
        int nk = n0 + k;
        ax[k] = 0.f; ay[k] = 0.f;
        if (nk < n) {
            float2 v = __half22float2(*(const __half2*)&hp[(size_t)nk * F + 2 * f2]);
            ax[k] = v.x; ay[k] = v.y;
        }
        int nc = min(nk, n - 1);
        cur[k]  = rps[nc];               // start of range 0
        end_[k] = rps[(size_t)n + nc];   // start of range 1 == end of range 0
    }
    for (int r = 0; r < NR; ++r) {
        if (r + 1 < NR) {
#pragma unroll
            for (int k = 0; k < K; ++k) {
                int nc = min(n0 + k, n - 1);
                nxt[k] = rps[(size_t)(r + 2) * n + nc];   // end of range r+1
            }
        }
        int ml = 0;
#pragma unroll
        for (int k = 0; k < K; ++k) ml = max(ml, end_[k] - cur[k]);
        for (int j = 0; j < ml; j += 2) {
            int c0[K], c1[K];
#pragma unroll
            for (int k = 0; k < K; ++k) {
                int lim = max(end_[k] - 1, 0);   // clamp: repeat last edge (L1 hit)
                int i0 = min(cur[k],     lim);
                int i1 = min(cur[k] + 1, lim);
                c0[k] = ld_nt_i32(&col[i0]);
                c1[k] = ld_nt_i32(&col[i1]);
            }
#pragma unroll
            for (int k = 0; k < K; ++k) {
                float2 v0 = __half22float2(*(const __half2*)&hp[(size_t)c0[k] * F + 2 * f2]);
                float2 v1 = __half22float2(*(const __half2*)&hp[(size_t)c1[k] * F + 2 * f2]);
                bool p0 = cur[k]     < end_[k];
                bool p1 = cur[k] + 1 < end_[k];
                ax[k] += p0 ? v0.x : 0.f;
                ay[k] += p0 ? v0.y : 0.f;
                ax[k] += p1 ? v1.x : 0.f;
                ay[k] += p1 ? v1.y : 0.f;
                cur[k] += 2;
            }
        }
        if (r + 1 < NR) {
#pragma unroll
            for (int k = 0; k < K; ++k) { cur[k] = end_[k]; end_[k] = nxt[k]; }
        }
        __syncthreads();   // keep the block's waves range-phased
    }
#pragma unroll
    for (int k = 0; k < K; ++k) {
        int nk = n0 + k;
        if (nk < n) {
            float s = dinv[nk];
            float rx = ax[k] * s, ry = ay[k] * s;
            if (ACT) {
                rx = fmaxf(rx + bias[2 * f2], 0.f);
                ry = fmaxf(ry + bias[2 * f2 + 1], 0.f);
            }
            union { float2 f; unsigned long long u; } o;
            o.f = make_float2(rx, ry);
            __builtin_nontemporal_store(o.u,
                (unsigned long long*)&agg[(size_t)nk * F + 2 * f2]);
        }
    }
}

// ---------------- mean pool ----------------
__global__ __launch_bounds__(256) void pool_kernel(
        const float* __restrict__ h3, const int* __restrict__ batch,
        int n, float* __restrict__ pool) {
    int g = blockIdx.x;
    int lo = 0, hi = n;
    while (lo < hi) { int m = (lo + hi) >> 1; if (batch[m] < g) lo = m + 1; else hi = m; }
    int s = lo;
    hi = n;
    while (lo < hi) { int m = (lo + hi) >> 1; if (batch[m] < g + 1) lo = m + 1; else hi = m; }
    int e = lo;
    constexpr int F = OUT3;
    int ln = threadIdx.x / F;
    int f  = threadIdx.x % F;
    float acc = 0.f;
    for (int i = s + ln; i < e; i += 8)
        acc += h3[(size_t)i * F + f];
    __shared__ float red[8][F];
    red[ln][f] = acc;
    __syncthreads();
    if (ln == 0) {
        float t = 0.f;
#pragma unroll
        for (int j = 0; j < 8; ++j) t += red[j][f];
        float cnt = (float)((e - s) > 0 ? (e - s) : 1);
        pool[g * F + f] = t / cnt;
    }
}

// ---------------- head ----------------
__global__ __launch_bounds__(256) void head_kernel(
        const float* __restrict__ pool, const float* __restrict__ Wh1,
        const float* __restrict__ bh1, const float* __restrict__ Wh2,
        const float* __restrict__ bh2, float* __restrict__ out) {
    __shared__ float sW1[32 * 32];
    __shared__ float sb1[32];
    __shared__ float sW2[32];
    int t = threadIdx.x;
    for (int i = t; i < 1024; i += 256) sW1[i] = Wh1[i];
    if (t < 32) { sb1[t] = bh1[t]; sW2[t] = Wh2[t]; }
    __syncthreads();
    int g = t;
    float y = bh2[0];
    const float* p = &pool[g * 32];
#pragma unroll 4
    for (int j = 0; j < 32; ++j) {
        float a = sb1[j];
#pragma unroll
        for (int k = 0; k < 32; ++k) a += p[k] * sW1[k * 32 + j];
        y += fmaxf(a, 0.f) * sW2[j];
    }
    out[g] = y;
}

extern "C" void kernel_launch(void* const* d_in, const int* in_sizes, int n_in,
                              void* d_out, int out_size, void* d_ws, size_t ws_size,
                              hipStream_t stream) {
    const float* x    = (const float*)d_in[0];
    const int*   ei   = (const int*)  d_in[1];
    const int*   batch= (const int*)  d_in[2];
    const float* W1   = (const float*)d_in[3];
    const float* b1   = (const float*)d_in[4];
    const float* W2   = (const float*)d_in[5];
    const float* b2   = (const float*)d_in[6];
    const float* W3   = (const float*)d_in[7];
    const float* b3   = (const float*)d_in[8];
    const float* Wh1  = (const float*)d_in[9];
    const float* bh1  = (const float*)d_in[10];
    const float* Wh2  = (const float*)d_in[11];
    const float* bh2  = (const float*)d_in[12];
    float* out = (float*)d_out;

    const int N = in_sizes[0] / IN_DIM;
    const int E = in_sizes[1] / 2;
    const int* src = ei;
    const int* dst = ei + E;
    const int NB = (N + BK_NODES - 1) >> BK_LOG;

    // workspace layout (all 4B elements; half buffers alias the fp32 ones)
    char* base = (char*)d_ws;
    unsigned int* ebuf = (unsigned int*)base;       base += (size_t)E * 4;
    int*   bhist   = (int*)base;                    base += (size_t)MAXB * 4;
    int*   bbase   = (int*)base;                    base += (size_t)(MAXB + 1) * 4;
    int*   cursor  = (int*)base;                    base += (size_t)MAXB * 4;
    int*   rps     = (int*)base;                    base += (size_t)(NR + 1) * N * 4;
    float* dinv    = (float*)base;                  base += (size_t)N * 4;
    float* W1p     = (float*)base;                  base += (size_t)32 * HID * 4;
    float* bufA    = (float*)base;                  base += (size_t)N * HID * 4;
    float* bufB    = (float*)base;                  base += (size_t)N * HID * 4;
    float* pool    = (float*)base;

    // ---- CSR build (coalesced counting sort, cols grouped by src-range) ----
    hipMemsetAsync(bhist, 0, (size_t)MAXB * sizeof(int), stream);
    bucket_hist<<<(E + 8191) / 8192, 256, 0, stream>>>(dst, bhist, E);
    bucket_scan<<<1, 256, 0, stream>>>(bhist, bbase, cursor, NB, E);
    partition_kernel<<<(E + EPB1 - 1) / EPB1, 256, 0, stream>>>(src, dst, cursor, ebuf, E);
    bucket_csr_kernel<<<NB, 256, 0, stream>>>(ebuf, bbase, dinv, rps, N);
    const int* col = (const int*)ebuf;

    // gather grid sizing: nodes per block = 4 waves * SPW * K
    constexpr int K64 = 6, K32 = 6;
    const int npb64 = 4 * 2 * K64;   // 48
    const int npb32 = 4 * 4 * K32;   // 96
    const int blocks64 = (N + npb64 - 1) / npb64;
    const int blocks32 = (N + npb32 - 1) / npb32;

    // ---- layer 1 (reordered): aggX = A_hat Xp' ; h1 = relu(aggX @ W1p + b1)
    // xp (half) in bufB; aggX (fp32) in bufA; h1 (fp32) back in bufB.
    padx_kernel<<<((size_t)N * 16 + 255) / 256, 256, 0, stream>>>(x, dinv, (__half*)bufB, N);
    padw_kernel<<<(32 * HID + 255) / 256, 256, 0, stream>>>(W1, W1p);
    gather_kernel<32, false, K32><<<blocks32, 256, 0, stream>>>((const __half*)bufB, dinv, rps, col, nullptr, bufA, N);
    gemm_kernel<32, HID, true, false><<<(N + 15) / 16, 256, 0, stream>>>(bufA, W1p, b1, nullptr, bufB, N);

    // ---- layer 2: t2' = half((h1 @ W2)*dinv) ; h2 = relu(dinv*(sum t2') + b2)
    gemm_kernel<HID, HID, false, true><<<(N + 15) / 16, 256, 0, stream>>>(bufB, W2, nullptr, dinv, bufA, N);
    gather_kernel<HID, true, K64><<<blocks64, 256, 0, stream>>>((const __half*)bufA, dinv, rps, col, b2, bufB, N);

    // ---- layer 3: t3' = half((h2 @ W3)*dinv) ; h3 = relu(dinv*(sum t3') + b3)
    gemm_kernel<HID, OUT3, false, true><<<(N + 31) / 32, 256, 0, stream>>>(bufB, W3, nullptr, dinv, bufA, N);
    gather_kernel<OUT3, true, K32><<<blocks32, 256, 0, stream>>>((const __half*)bufA, dinv, rps, col, b3, bufB, N);

    // ---- pool + head ----
    pool_kernel<<<256, 256, 0, stream>>>(bufB, batch, N, pool);
    head_kernel<<<1, 256, 0, stream>>>(pool, Wh1, bh1, Wh2, bh2, out);
}